// Round 1
// baseline (227.954 us; speedup 1.0000x reference)
//
#include <hip/hip_runtime.h>
#include <hip/hip_bf16.h>
#include <math.h>

typedef short bf16x8 __attribute__((ext_vector_type(8)));
typedef float f32x4 __attribute__((ext_vector_type(4)));

#define D 128
#define SQ 8192
#define SKV 8192

__device__ __forceinline__ ushort f2bf(float x) {
  union { float f; unsigned u; } v; v.f = x;
  unsigned r = v.u + 0x7fffu + ((v.u >> 16) & 1u);
  return (ushort)(r >> 16);
}
__device__ __forceinline__ float bf2f(ushort h) {
  union { unsigned u; float f; } v; v.u = ((unsigned)h) << 16;
  return v.f;
}

// (D x S) f32 row-major  ->  (S x D) bf16 hi/lo row-major (transpose + split)
__global__ void prep_transpose(const float* __restrict__ src,
                               ushort* __restrict__ dhi, ushort* __restrict__ dlo) {
  __shared__ float tile[32][33];
  int s0 = blockIdx.x * 32;
  int d0 = blockIdx.y * 32;
  int t = threadIdx.x;
  int g = t >> 5, l = t & 31;
#pragma unroll
  for (int j = 0; j < 4; ++j) {
    int dl = g * 4 + j;
    tile[dl][l] = src[(size_t)(d0 + dl) * SQ + s0 + l];
  }
  __syncthreads();
#pragma unroll
  for (int j = 0; j < 4; ++j) {
    int sl = g * 4 + j;
    float x = tile[l][sl];
    ushort hi = f2bf(x);
    float lo = x - bf2f(hi);
    dhi[(size_t)(s0 + sl) * D + d0 + l] = hi;
    dlo[(size_t)(s0 + sl) * D + d0 + l] = f2bf(lo);
  }
}

// plain f32 -> bf16 convert (keeps (D x SKV) layout)
__global__ void conv_v(const float* __restrict__ src, ushort* __restrict__ dst) {
  int i = (blockIdx.x * 256 + threadIdx.x) * 4;
  float4 v = *(const float4*)(src + i);
  ushort4 o;
  o.x = f2bf(v.x); o.y = f2bf(v.y); o.z = f2bf(v.z); o.w = f2bf(v.w);
  *(ushort4*)(dst + i) = o;
}

__global__ void flash_fwd(const ushort* __restrict__ QThi, const ushort* __restrict__ QTlo,
                          const ushort* __restrict__ KThi, const ushort* __restrict__ KTlo,
                          const ushort* __restrict__ VB,
                          float* __restrict__ Opart, float* __restrict__ Mst,
                          float* __restrict__ Lst, int splitLen) {
  __shared__ ushort Khi[32][136];   // 128 cols + 8 pad: stride 272B, 16B aligned, bank-uniform
  __shared__ ushort Klo[32][136];
  __shared__ ushort Vt[128][40];    // 32 cols + 8 pad
  __shared__ ushort Pl[4][16][40];  // per-wave P tile (16 x 32 + pad)

  const int tid = threadIdx.x;
  const int w = tid >> 6;
  const int lane = tid & 63;
  const int lr = lane & 15;
  const int lg = lane >> 4;
  const int qb = blockIdx.x;
  const int split = blockIdx.y;

  const int qrow = qb * 64 + w * 16 + lr;

  // Q fragments (A operand), hoisted: 4 k-chunks of 32, hi+lo
  bf16x8 qhi[4], qlo[4];
#pragma unroll
  for (int c = 0; c < 4; ++c) {
    qhi[c] = *(const bf16x8*)(QThi + (size_t)qrow * D + c * 32 + lg * 8);
    qlo[c] = *(const bf16x8*)(QTlo + (size_t)qrow * D + c * 32 + lg * 8);
  }

  f32x4 Oacc[8];
#pragma unroll
  for (int dt = 0; dt < 8; ++dt) Oacc[dt] = (f32x4){0.f, 0.f, 0.f, 0.f};
  float mrun[4] = {-INFINITY, -INFINITY, -INFINITY, -INFINITY};
  float lrun[4] = {0.f, 0.f, 0.f, 0.f};

  const int kvBase = split * splitLen;
  const int nsteps = splitLen / 32;

  for (int it = 0; it < nsteps; ++it) {
    const int kv0 = kvBase + it * 32;

    // ---- stage K hi/lo tiles (32 x 128 each) ----
#pragma unroll
    for (int i = 0; i < 4; ++i) {
      int s = i * 256 + tid;
      int r = (s >> 4) & 31;
      int c = s & 15;
      const ushort* srcp = ((s >> 9) ? KTlo : KThi) + (size_t)(kv0 + r) * D + c * 8;
      bf16x8 tmp = *(const bf16x8*)srcp;
      ushort* dstp = (s >> 9) ? &Klo[r][c * 8] : &Khi[r][c * 8];
      *(bf16x8*)dstp = tmp;
    }
    // ---- stage V tile (128 x 32) ----
#pragma unroll
    for (int i = 0; i < 2; ++i) {
      int s = i * 256 + tid;
      int r = s >> 2;
      int c = s & 3;
      bf16x8 tmp = *(const bf16x8*)(VB + (size_t)r * SKV + kv0 + c * 8);
      *(bf16x8*)&Vt[r][c * 8] = tmp;
    }
    __syncthreads();

    // ---- S = Q^T K for this wave's 16 rows x 32 kv (split bf16: 3 MFMAs) ----
    f32x4 st[2];
    st[0] = (f32x4){0.f, 0.f, 0.f, 0.f};
    st[1] = (f32x4){0.f, 0.f, 0.f, 0.f};
#pragma unroll
    for (int kt = 0; kt < 2; ++kt) {
#pragma unroll
      for (int c = 0; c < 4; ++c) {
        bf16x8 bh = *(const bf16x8*)&Khi[kt * 16 + lr][c * 32 + lg * 8];
        bf16x8 bl = *(const bf16x8*)&Klo[kt * 16 + lr][c * 32 + lg * 8];
        st[kt] = __builtin_amdgcn_mfma_f32_16x16x32_bf16(qhi[c], bh, st[kt], 0, 0, 0);
        st[kt] = __builtin_amdgcn_mfma_f32_16x16x32_bf16(qlo[c], bh, st[kt], 0, 0, 0);
        st[kt] = __builtin_amdgcn_mfma_f32_16x16x32_bf16(qhi[c], bl, st[kt], 0, 0, 0);
      }
    }

    // ---- online softmax (rows live in lanes as C-layout: row = lg*4+r) ----
    float mt[4], p0[4], p1[4], ls[4], scale[4];
#pragma unroll
    for (int r = 0; r < 4; ++r) mt[r] = fmaxf(st[0][r], st[1][r]);
#pragma unroll
    for (int off = 1; off < 16; off <<= 1) {
#pragma unroll
      for (int r = 0; r < 4; ++r) mt[r] = fmaxf(mt[r], __shfl_xor(mt[r], off));
    }
#pragma unroll
    for (int r = 0; r < 4; ++r) {
      float mn = fmaxf(mrun[r], mt[r]);
      scale[r] = __expf(mrun[r] - mn);   // first iter: exp(-inf) = 0
      mrun[r] = mn;
      p0[r] = __expf(st[0][r] - mn);
      p1[r] = __expf(st[1][r] - mn);
      ls[r] = p0[r] + p1[r];
    }
#pragma unroll
    for (int off = 1; off < 16; off <<= 1) {
#pragma unroll
      for (int r = 0; r < 4; ++r) ls[r] += __shfl_xor(ls[r], off);
    }
#pragma unroll
    for (int r = 0; r < 4; ++r) lrun[r] = lrun[r] * scale[r] + ls[r];
#pragma unroll
    for (int dt = 0; dt < 8; ++dt) {
#pragma unroll
      for (int r = 0; r < 4; ++r) Oacc[dt][r] *= scale[r];
    }

    // ---- P -> per-wave LDS (bf16), transposing C-layout to A-frag layout ----
#pragma unroll
    for (int r = 0; r < 4; ++r) {
      Pl[w][lg * 4 + r][lr] = f2bf(p0[r]);
      Pl[w][lg * 4 + r][16 + lr] = f2bf(p1[r]);
    }
    // per-wave DS ops are in-order; no barrier needed for own-wave RAW
    bf16x8 pa = *(const bf16x8*)&Pl[w][lr][lg * 8];
#pragma unroll
    for (int dt = 0; dt < 8; ++dt) {
      bf16x8 vb = *(const bf16x8*)&Vt[dt * 16 + lr][lg * 8];
      Oacc[dt] = __builtin_amdgcn_mfma_f32_16x16x32_bf16(pa, vb, Oacc[dt], 0, 0, 0);
    }
    __syncthreads();
  }

  // ---- epilogue: write partial O and stats ----
  const int orow = qb * 64 + w * 16 + lg * 4;
  float* Op = Opart + (size_t)split * SQ * D;
#pragma unroll
  for (int dt = 0; dt < 8; ++dt) {
#pragma unroll
    for (int r = 0; r < 4; ++r) {
      Op[(size_t)(orow + r) * D + dt * 16 + lr] = Oacc[dt][r];
    }
  }
  if (lr == 0) {
#pragma unroll
    for (int r = 0; r < 4; ++r) {
      Mst[split * SQ + orow + r] = mrun[r];
      Lst[split * SQ + orow + r] = lrun[r];
    }
  }
}

__global__ void combine(const float* __restrict__ Opart, const float* __restrict__ Mst,
                        const float* __restrict__ Lst, float* __restrict__ out, int nsplit) {
  int idx = blockIdx.x * 256 + threadIdx.x;
  int qi = idx >> 7;
  float M = -INFINITY;
  for (int s = 0; s < nsplit; ++s) M = fmaxf(M, Mst[s * SQ + qi]);
  float num = 0.f, den = 0.f;
  for (int s = 0; s < nsplit; ++s) {
    float wgt = __expf(Mst[s * SQ + qi] - M);
    den += wgt * Lst[s * SQ + qi];
    num += wgt * Opart[(size_t)s * SQ * D + idx];
  }
  out[idx] = num / den;
}

extern "C" void kernel_launch(void* const* d_in, const int* in_sizes, int n_in,
                              void* d_out, int out_size, void* d_ws, size_t ws_size,
                              hipStream_t stream) {
  const float* q = (const float*)d_in[0];
  const float* k = (const float*)d_in[1];
  const float* v = (const float*)d_in[2];
  float* out = (float*)d_out;

  char* ws = (char*)d_ws;
  const size_t mat = (size_t)SQ * D * 2;  // 2 MB per bf16 matrix
  ushort* QThi = (ushort*)(ws);
  ushort* QTlo = (ushort*)(ws + mat);
  ushort* KThi = (ushort*)(ws + 2 * mat);
  ushort* KTlo = (ushort*)(ws + 3 * mat);
  ushort* VB   = (ushort*)(ws + 4 * mat);
  char* rest = ws + 5 * mat;
  size_t avail = (ws_size > 5 * mat) ? (ws_size - 5 * mat) : 0;

  const size_t opartSz = (size_t)SQ * D * 4;  // 4 MB per split
  const size_t statSz  = (size_t)SQ * 4;
  int nsplit = 4;
  while (nsplit > 1 && (size_t)nsplit * (opartSz + 2 * statSz) > avail) nsplit >>= 1;

  float* Opart = (float*)rest;
  float* Mst = (float*)(rest + (size_t)nsplit * opartSz);
  float* Lst = (float*)(rest + (size_t)nsplit * opartSz + (size_t)nsplit * statSz);

  prep_transpose<<<dim3(SQ / 32, D / 32), 256, 0, stream>>>(q, QThi, QTlo);
  prep_transpose<<<dim3(SKV / 32, D / 32), 256, 0, stream>>>(k, KThi, KTlo);
  conv_v<<<(D * SKV) / (256 * 4), 256, 0, stream>>>(v, VB);
  flash_fwd<<<dim3(SQ / 64, nsplit), 256, 0, stream>>>(QThi, QTlo, KThi, KTlo, VB,
                                                       Opart, Mst, Lst, SKV / nsplit);
  combine<<<(SQ * D) / 256, 256, 0, stream>>>(Opart, Mst, Lst, out, nsplit);
}

// Round 3
// 189.535 us; speedup vs baseline: 1.2027x; 1.2027x over previous
//
#include <hip/hip_runtime.h>
#include <hip/hip_bf16.h>
#include <math.h>

typedef short bf16x8 __attribute__((ext_vector_type(8)));
typedef float f32x4 __attribute__((ext_vector_type(4)));

#define D 128
#define SQ 8192
#define SKV 8192

__device__ __forceinline__ ushort f2bf(float x) {
  union { float f; unsigned u; } v; v.f = x;
  unsigned r = v.u + 0x7fffu + ((v.u >> 16) & 1u);
  return (ushort)(r >> 16);
}
__device__ __forceinline__ float bf2f(ushort h) {
  union { unsigned u; float f; } v; v.u = ((unsigned)h) << 16;
  return v.f;
}

// (D x S) f32 row-major  ->  (S x D) bf16 hi/lo row-major (transpose + split)
__global__ void prep_transpose(const float* __restrict__ src,
                               ushort* __restrict__ dhi, ushort* __restrict__ dlo) {
  __shared__ float tile[32][33];
  int s0 = blockIdx.x * 32;
  int d0 = blockIdx.y * 32;
  int t = threadIdx.x;
  int g = t >> 5, l = t & 31;
#pragma unroll
  for (int j = 0; j < 4; ++j) {
    int dl = g * 4 + j;
    tile[dl][l] = src[(size_t)(d0 + dl) * SQ + s0 + l];
  }
  __syncthreads();
#pragma unroll
  for (int j = 0; j < 4; ++j) {
    int sl = g * 4 + j;
    float x = tile[l][sl];
    ushort hi = f2bf(x);
    float lo = x - bf2f(hi);
    dhi[(size_t)(s0 + sl) * D + d0 + l] = hi;
    dlo[(size_t)(s0 + sl) * D + d0 + l] = f2bf(lo);
  }
}

// plain f32 -> bf16 convert (keeps (D x SKV) layout)
__global__ void conv_v(const float* __restrict__ src, ushort* __restrict__ dst) {
  int i = (blockIdx.x * 256 + threadIdx.x) * 4;
  float4 v = *(const float4*)(src + i);
  ushort4 o;
  o.x = f2bf(v.x); o.y = f2bf(v.y); o.z = f2bf(v.z); o.w = f2bf(v.w);
  *(ushort4*)(dst + i) = o;
}

__global__ __launch_bounds__(256, 2)
void flash_fwd(const ushort* __restrict__ QThi, const ushort* __restrict__ QTlo,
               const ushort* __restrict__ KThi, const ushort* __restrict__ KTlo,
               const ushort* __restrict__ VB,
               float* __restrict__ Opart, float* __restrict__ Mst,
               float* __restrict__ Lst, int splitLen) {
  // K tiles 64x128 bf16, hi/lo, double-buffered. XOR-swizzled (byte ^= (row&7)<<4)
  // so ds_read_b128 fragment reads hit 8 distinct 16B slots -> conflict-free.
  __shared__ ushort Khi[2][64][128];
  __shared__ ushort Klo[2][64][128];
  __shared__ ushort Pl[4][16][72];   // per-wave P tile (16 x 64 + 8 pad; stride 144B = 16B-aligned)

  const int tid = threadIdx.x;
  const int w = tid >> 6;
  const int lane = tid & 63;
  const int lr = lane & 15;
  const int lg = lane >> 4;
  const int qb = blockIdx.x;
  const int split = blockIdx.y;
  const int qrow = qb * 64 + w * 16 + lr;

  // Q fragments (A operand), hoisted: 4 k-chunks of 32, hi+lo
  bf16x8 qhi[4], qlo[4];
#pragma unroll
  for (int c = 0; c < 4; ++c) {
    qhi[c] = *(const bf16x8*)(QThi + (size_t)qrow * D + c * 32 + lg * 8);
    qlo[c] = *(const bf16x8*)(QTlo + (size_t)qrow * D + c * 32 + lg * 8);
  }

  f32x4 Oacc[8];
#pragma unroll
  for (int dt = 0; dt < 8; ++dt) Oacc[dt] = (f32x4){0.f, 0.f, 0.f, 0.f};
  float mrun[4] = {-INFINITY, -INFINITY, -INFINITY, -INFINITY};
  float lrun[4] = {0.f, 0.f, 0.f, 0.f};

  const int kvBase = split * splitLen;
  const int nsteps = splitLen / 64;

  // ---- staging helpers: K hi+lo 64x128 tile = 2048 16B-chunks, 8 per thread ----
  bf16x8 stg[8];
#define LOADREG(KV0)                                                          \
  {                                                                           \
    _Pragma("unroll")                                                         \
    for (int i = 0; i < 8; ++i) {                                             \
      int cidx = i * 256 + tid;                                               \
      int idx = cidx & 1023;                                                  \
      int row = idx >> 4;                                                     \
      int ch = idx & 15;                                                      \
      const ushort* srcp = ((cidx >> 10) ? KTlo : KThi) +                     \
                           (size_t)((KV0) + row) * D + ch * 8;                \
      stg[i] = *(const bf16x8*)srcp;                                          \
    }                                                                         \
  }
#define WRITELDS(NB)                                                          \
  {                                                                           \
    _Pragma("unroll")                                                         \
    for (int i = 0; i < 8; ++i) {                                             \
      int cidx = i * 256 + tid;                                               \
      int idx = cidx & 1023;                                                  \
      int row = idx >> 4;                                                     \
      int ch = idx & 15;                                                      \
      char* basep = (char*)((cidx >> 10) ? &Klo[NB][0][0] : &Khi[NB][0][0]);  \
      *(bf16x8*)(basep + row * 256 + ((ch * 16) ^ ((row & 7) << 4))) = stg[i];\
    }                                                                         \
  }

  LOADREG(kvBase);
  WRITELDS(0);
  __syncthreads();
  int cur = 0;

  const int swz = (lr & 7) << 4;

  for (int it = 0; it < nsteps; ++it) {
    const int kv0 = kvBase + it * 64;
    const bool more = (it + 1 < nsteps);
    if (more) LOADREG(kv0 + 64);  // issue next-tile global loads early (T14)

    // ---- S = Q^T K for this wave's 16 rows x 64 kv (split bf16: 3 MFMAs) ----
    f32x4 st[4];
#pragma unroll
    for (int kt = 0; kt < 4; ++kt) st[kt] = (f32x4){0.f, 0.f, 0.f, 0.f};
    const char* khB = (const char*)&Khi[cur][0][0];
    const char* klB = (const char*)&Klo[cur][0][0];
#pragma unroll
    for (int kt = 0; kt < 4; ++kt) {
      const int rowoff = (kt * 16 + lr) * 256;
#pragma unroll
      for (int c = 0; c < 4; ++c) {
        const int boff = rowoff + ((c * 64 + lg * 16) ^ swz);
        bf16x8 bh = *(const bf16x8*)(khB + boff);
        bf16x8 bl = *(const bf16x8*)(klB + boff);
        st[kt] = __builtin_amdgcn_mfma_f32_16x16x32_bf16(qhi[c], bh, st[kt], 0, 0, 0);
        st[kt] = __builtin_amdgcn_mfma_f32_16x16x32_bf16(qlo[c], bh, st[kt], 0, 0, 0);
        st[kt] = __builtin_amdgcn_mfma_f32_16x16x32_bf16(qhi[c], bl, st[kt], 0, 0, 0);
      }
    }

    // ---- online softmax (C-layout: q-row = lg*4+r, kv col = kt*16 + lr) ----
    float mt[4];
#pragma unroll
    for (int r = 0; r < 4; ++r)
      mt[r] = fmaxf(fmaxf(st[0][r], st[1][r]), fmaxf(st[2][r], st[3][r]));
#pragma unroll
    for (int off = 1; off < 16; off <<= 1) {
#pragma unroll
      for (int r = 0; r < 4; ++r) mt[r] = fmaxf(mt[r], __shfl_xor(mt[r], off));
    }
    float scale[4], p[4][4], ls[4];
#pragma unroll
    for (int r = 0; r < 4; ++r) {
      float mn = fmaxf(mrun[r], mt[r]);
      scale[r] = __expf(mrun[r] - mn);   // first iter: exp(-inf) = 0
      mrun[r] = mn;
#pragma unroll
      for (int kt = 0; kt < 4; ++kt) p[kt][r] = __expf(st[kt][r] - mn);
      ls[r] = (p[0][r] + p[1][r]) + (p[2][r] + p[3][r]);
    }
#pragma unroll
    for (int off = 1; off < 16; off <<= 1) {
#pragma unroll
      for (int r = 0; r < 4; ++r) ls[r] += __shfl_xor(ls[r], off);
    }
#pragma unroll
    for (int r = 0; r < 4; ++r) lrun[r] = lrun[r] * scale[r] + ls[r];

    // ---- P -> per-wave LDS (bf16), C-layout -> A-frag layout ----
#pragma unroll
    for (int kt = 0; kt < 4; ++kt) {
#pragma unroll
      for (int r = 0; r < 4; ++r) {
        Pl[w][lg * 4 + r][kt * 16 + lr] = f2bf(p[kt][r]);
      }
    }
    // per-wave DS ops are in-order; no barrier needed for own-wave RAW
    bf16x8 pa0 = *(const bf16x8*)&Pl[w][lr][lg * 8];
    bf16x8 pa1 = *(const bf16x8*)&Pl[w][lr][32 + lg * 8];

#pragma unroll
    for (int dt = 0; dt < 8; ++dt) {
#pragma unroll
      for (int r = 0; r < 4; ++r) Oacc[dt][r] *= scale[r];
    }

    // ---- PV: V B-fragments straight from global (L1/L2-resident) ----
#pragma unroll
    for (int dt = 0; dt < 8; ++dt) {
      const ushort* vrow = VB + (size_t)(dt * 16 + lr) * SKV + kv0;
      bf16x8 v0 = *(const bf16x8*)(vrow + lg * 8);
      bf16x8 v1 = *(const bf16x8*)(vrow + 32 + lg * 8);
      Oacc[dt] = __builtin_amdgcn_mfma_f32_16x16x32_bf16(pa0, v0, Oacc[dt], 0, 0, 0);
      Oacc[dt] = __builtin_amdgcn_mfma_f32_16x16x32_bf16(pa1, v1, Oacc[dt], 0, 0, 0);
    }

    if (more) WRITELDS(cur ^ 1);  // write next tile; nobody reads it until after barrier
    __syncthreads();
    cur ^= 1;
  }

  // ---- epilogue: write partial O and stats ----
  const int orow = qb * 64 + w * 16 + lg * 4;
  float* Op = Opart + (size_t)split * SQ * D;
#pragma unroll
  for (int dt = 0; dt < 8; ++dt) {
#pragma unroll
    for (int r = 0; r < 4; ++r) {
      Op[(size_t)(orow + r) * D + dt * 16 + lr] = Oacc[dt][r];
    }
  }
  if (lr == 0) {
#pragma unroll
    for (int r = 0; r < 4; ++r) {
      Mst[split * SQ + orow + r] = mrun[r];
      Lst[split * SQ + orow + r] = lrun[r];
    }
  }
}

__global__ void combine(const float* __restrict__ Opart, const float* __restrict__ Mst,
                        const float* __restrict__ Lst, float* __restrict__ out, int nsplit) {
  int idx = blockIdx.x * 256 + threadIdx.x;
  int qi = idx >> 7;
  float M = -INFINITY;
  for (int s = 0; s < nsplit; ++s) M = fmaxf(M, Mst[s * SQ + qi]);
  float num = 0.f, den = 0.f;
  for (int s = 0; s < nsplit; ++s) {
    float wgt = __expf(Mst[s * SQ + qi] - M);
    den += wgt * Lst[s * SQ + qi];
    num += wgt * Opart[(size_t)s * SQ * D + idx];
  }
  out[idx] = num / den;
}

extern "C" void kernel_launch(void* const* d_in, const int* in_sizes, int n_in,
                              void* d_out, int out_size, void* d_ws, size_t ws_size,
                              hipStream_t stream) {
  const float* q = (const float*)d_in[0];
  const float* k = (const float*)d_in[1];
  const float* v = (const float*)d_in[2];
  float* out = (float*)d_out;

  char* ws = (char*)d_ws;
  const size_t mat = (size_t)SQ * D * 2;  // 2 MB per bf16 matrix
  ushort* QThi = (ushort*)(ws);
  ushort* QTlo = (ushort*)(ws + mat);
  ushort* KThi = (ushort*)(ws + 2 * mat);
  ushort* KTlo = (ushort*)(ws + 3 * mat);
  ushort* VB   = (ushort*)(ws + 4 * mat);
  char* rest = ws + 5 * mat;
  size_t avail = (ws_size > 5 * mat) ? (ws_size - 5 * mat) : 0;

  const size_t opartSz = (size_t)SQ * D * 4;  // 4 MB per split
  const size_t statSz  = (size_t)SQ * 4;
  int nsplit = 4;   // grid 512 = exactly 2 blocks/CU with 73KB LDS -> perfectly packed
  while (nsplit > 1 && (size_t)nsplit * (opartSz + 2 * statSz) > avail) nsplit >>= 1;

  float* Opart = (float*)rest;
  float* Mst = (float*)(rest + (size_t)nsplit * opartSz);
  float* Lst = (float*)(rest + (size_t)nsplit * opartSz + (size_t)nsplit * statSz);

  prep_transpose<<<dim3(SQ / 32, D / 32), 256, 0, stream>>>(q, QThi, QTlo);
  prep_transpose<<<dim3(SKV / 32, D / 32), 256, 0, stream>>>(k, KThi, KTlo);
  conv_v<<<(D * SKV) / (256 * 4), 256, 0, stream>>>(v, VB);
  flash_fwd<<<dim3(SQ / 64, nsplit), 256, 0, stream>>>(QThi, QTlo, KThi, KTlo, VB,
                                                       Opart, Mst, Lst, SKV / nsplit);
  combine<<<(SQ * D) / 256, 256, 0, stream>>>(Opart, Mst, Lst, out, nsplit);
}

// Round 4
// 122.526 us; speedup vs baseline: 1.8605x; 1.5469x over previous
//
#include <hip/hip_runtime.h>
#include <hip/hip_bf16.h>
#include <math.h>

typedef short bf16x8 __attribute__((ext_vector_type(8)));
typedef float f32x4 __attribute__((ext_vector_type(4)));
typedef float f32x16 __attribute__((ext_vector_type(16)));

#define D 128
#define SQ 8192
#define SKV 8192
#define BQ 128    // q-rows per block (4 waves x 32)
#define BKV 64

__device__ __forceinline__ ushort f2bf(float x) {
  union { float f; unsigned u; } v; v.f = x;
  unsigned r = v.u + 0x7fffu + ((v.u >> 16) & 1u);
  return (ushort)(r >> 16);
}
__device__ __forceinline__ float bf2f(ushort h) {
  union { unsigned u; float f; } v; v.u = ((unsigned)h) << 16;
  return v.f;
}
// pack two f32 -> one dword of 2 bf16 (lo in low half)
__device__ __forceinline__ unsigned pkbf(float a, float b) {
  return (unsigned)f2bf(a) | ((unsigned)f2bf(b) << 16);
}
// v_permlane32_swap_b32: swaps a.lanes[32:63] <-> b.lanes[0:31]
__device__ __forceinline__ void pl32swap(unsigned& a, unsigned& b) {
  asm("v_permlane32_swap_b32 %0, %1" : "+v"(a), "+v"(b));
}

// (D x S) f32 row-major  ->  (S x D) bf16 hi/lo row-major (transpose + split)
__global__ void prep_transpose(const float* __restrict__ src,
                               ushort* __restrict__ dhi, ushort* __restrict__ dlo) {
  __shared__ float tile[32][33];
  int s0 = blockIdx.x * 32;
  int d0 = blockIdx.y * 32;
  int t = threadIdx.x;
  int g = t >> 5, l = t & 31;
#pragma unroll
  for (int j = 0; j < 4; ++j) {
    int dl = g * 4 + j;
    tile[dl][l] = src[(size_t)(d0 + dl) * SQ + s0 + l];
  }
  __syncthreads();
#pragma unroll
  for (int j = 0; j < 4; ++j) {
    int sl = g * 4 + j;
    float x = tile[l][sl];
    ushort hi = f2bf(x);
    float lo = x - bf2f(hi);
    dhi[(size_t)(s0 + sl) * D + d0 + l] = hi;
    dlo[(size_t)(s0 + sl) * D + d0 + l] = f2bf(lo);
  }
}

// plain f32 -> bf16 convert (keeps (D x SKV) layout == V^T A-frag layout)
__global__ void conv_v(const float* __restrict__ src, ushort* __restrict__ dst) {
  int i = (blockIdx.x * 256 + threadIdx.x) * 4;
  float4 v = *(const float4*)(src + i);
  ushort4 o;
  o.x = f2bf(v.x); o.y = f2bf(v.y); o.z = f2bf(v.z); o.w = f2bf(v.w);
  *(ushort4*)(dst + i) = o;
}

__global__ __launch_bounds__(256, 2)
void flash_fwd(const ushort* __restrict__ QThi, const ushort* __restrict__ QTlo,
               const ushort* __restrict__ KThi, const ushort* __restrict__ KTlo,
               const ushort* __restrict__ VB,
               float* __restrict__ Opart, float* __restrict__ Mst,
               float* __restrict__ Lst, int splitLen) {
  // K tiles 64x128 bf16 hi/lo, double-buffered, XOR-swizzled (byte ^= (row&7)<<4):
  // A-frag b128 reads (32 rows x 2 slots) spread over 8 slots x 8 lanes -> conflict-free.
  __shared__ ushort Khi[2][64][128];
  __shared__ ushort Klo[2][64][128];

  const int tid = threadIdx.x;
  const int w = tid >> 6;
  const int lane = tid & 63;
  const int lc = lane & 31;   // q-row owner (QK C-col) / kv-row (A) / d-row (PV A)
  const int hi = lane >> 5;
  const int qb = blockIdx.x;
  const int split = blockIdx.y;
  const int qrow = qb * BQ + w * 32 + lc;

  // Q B-frags (col = q = lc, k = d = dstep*16 + hi*8 + j) -> contiguous in QT(SQ x D)
  bf16x8 qh[8], ql[8];
#pragma unroll
  for (int ds = 0; ds < 8; ++ds) {
    qh[ds] = *(const bf16x8*)(QThi + (size_t)qrow * D + ds * 16 + hi * 8);
    ql[ds] = *(const bf16x8*)(QTlo + (size_t)qrow * D + ds * 16 + hi * 8);
  }

  // O^T accumulators: 4 d-tiles of 32; C col = q = lc, row = d
  f32x16 Ot[4];
#pragma unroll
  for (int dt = 0; dt < 4; ++dt)
#pragma unroll
    for (int e = 0; e < 16; ++e) Ot[dt][e] = 0.f;
  float mrun = -INFINITY, lrun = 0.f;

  const int kvBase = split * splitLen;
  const int nsteps = splitLen / BKV;

  // ---- staging: K hi+lo 64x128 tile = 2048 16B-chunks, 8 per thread ----
  bf16x8 stg[8];
#define LOADREG(KV0)                                                          \
  {                                                                           \
    _Pragma("unroll")                                                         \
    for (int i = 0; i < 8; ++i) {                                             \
      int cidx = i * 256 + tid;                                               \
      int idx = cidx & 1023;                                                  \
      int row = idx >> 4;                                                     \
      int ch = idx & 15;                                                      \
      const ushort* srcp = ((cidx >> 10) ? KTlo : KThi) +                     \
                           (size_t)((KV0) + row) * D + ch * 8;                \
      stg[i] = *(const bf16x8*)srcp;                                          \
    }                                                                         \
  }
#define WRITELDS(NB)                                                          \
  {                                                                           \
    _Pragma("unroll")                                                         \
    for (int i = 0; i < 8; ++i) {                                             \
      int cidx = i * 256 + tid;                                               \
      int idx = cidx & 1023;                                                  \
      int row = idx >> 4;                                                     \
      int ch = idx & 15;                                                      \
      char* basep = (char*)((cidx >> 10) ? &Klo[NB][0][0] : &Khi[NB][0][0]);  \
      *(bf16x8*)(basep + row * 256 + ((ch * 16) ^ ((row & 7) << 4))) = stg[i];\
    }                                                                         \
  }

  LOADREG(kvBase);
  WRITELDS(0);
  __syncthreads();
  int cur = 0;

  const int rswz = (lc & 7) << 4;

  for (int it = 0; it < nsteps; ++it) {
    const int kv0 = kvBase + it * BKV;
    const bool more = (it + 1 < nsteps);
    if (more) LOADREG(kv0 + BKV);  // issue next-tile global loads early (T14)

    // ---- S^T = K Q^T (swapped): A = K^T rows (kv = t*32+lc), B = Q. Split-bf16, 3 MFMAs ----
    f32x16 s0, s1;
#pragma unroll
    for (int e = 0; e < 16; ++e) { s0[e] = 0.f; s1[e] = 0.f; }
    const char* khB = (const char*)&Khi[cur][0][0];
    const char* klB = (const char*)&Klo[cur][0][0];
#pragma unroll
    for (int ds = 0; ds < 8; ++ds) {
      const int col = (ds * 32 + hi * 16) ^ rswz;   // (row&7)==lc&7 for both kv tiles
      bf16x8 kh0 = *(const bf16x8*)(khB + lc * 256 + col);
      bf16x8 kl0 = *(const bf16x8*)(klB + lc * 256 + col);
      bf16x8 kh1 = *(const bf16x8*)(khB + (32 + lc) * 256 + col);
      bf16x8 kl1 = *(const bf16x8*)(klB + (32 + lc) * 256 + col);
      s0 = __builtin_amdgcn_mfma_f32_32x32x16_bf16(kh0, qh[ds], s0, 0, 0, 0);
      s0 = __builtin_amdgcn_mfma_f32_32x32x16_bf16(kh0, ql[ds], s0, 0, 0, 0);
      s0 = __builtin_amdgcn_mfma_f32_32x32x16_bf16(kl0, qh[ds], s0, 0, 0, 0);
      s1 = __builtin_amdgcn_mfma_f32_32x32x16_bf16(kh1, qh[ds], s1, 0, 0, 0);
      s1 = __builtin_amdgcn_mfma_f32_32x32x16_bf16(kh1, ql[ds], s1, 0, 0, 0);
      s1 = __builtin_amdgcn_mfma_f32_32x32x16_bf16(kl1, qh[ds], s1, 0, 0, 0);
    }

    // ---- in-register online softmax: q-row = lc; halves combine via shfl_xor 32 ----
    float mx = s0[0];
#pragma unroll
    for (int e = 1; e < 16; ++e) mx = fmaxf(mx, s0[e]);
#pragma unroll
    for (int e = 0; e < 16; ++e) mx = fmaxf(mx, s1[e]);
    mx = fmaxf(mx, __shfl_xor(mx, 32));

    // defer-max (T13, THR=8): skip O/l rescale while tile max stays within e^8
    if (!__all(mx - mrun <= 8.0f)) {
      float mn = fmaxf(mrun, mx);
      float sc = __expf(mrun - mn);   // first iter: exp(-inf) = 0
      mrun = mn;
      lrun *= sc;
#pragma unroll
      for (int dt = 0; dt < 4; ++dt)
#pragma unroll
        for (int e = 0; e < 16; ++e) Ot[dt][e] *= sc;
    }

#pragma unroll
    for (int e = 0; e < 16; ++e) {
      s0[e] = __expf(s0[e] - mrun);
      s1[e] = __expf(s1[e] - mrun);
    }
    float lsum = 0.f;
#pragma unroll
    for (int e = 0; e < 16; ++e) lsum += s0[e] + s1[e];
    lsum += __shfl_xor(lsum, 32);
    lrun += lsum;

    // ---- P -> bf16 PA/PB frags in-register (T12: pack + permlane32_swap) ----
    unsigned pk[8];
    bf16x8 pb[4];
    union { unsigned u[4]; bf16x8 v; } pbu;
#pragma unroll
    for (int j = 0; j < 8; ++j) pk[j] = pkbf(s0[2 * j], s0[2 * j + 1]);
    pl32swap(pk[0], pk[2]); pl32swap(pk[1], pk[3]);
    pl32swap(pk[4], pk[6]); pl32swap(pk[5], pk[7]);
    pbu.u[0] = pk[0]; pbu.u[1] = pk[1]; pbu.u[2] = pk[2]; pbu.u[3] = pk[3]; pb[0] = pbu.v;
    pbu.u[0] = pk[4]; pbu.u[1] = pk[5]; pbu.u[2] = pk[6]; pbu.u[3] = pk[7]; pb[1] = pbu.v;
#pragma unroll
    for (int j = 0; j < 8; ++j) pk[j] = pkbf(s1[2 * j], s1[2 * j + 1]);
    pl32swap(pk[0], pk[2]); pl32swap(pk[1], pk[3]);
    pl32swap(pk[4], pk[6]); pl32swap(pk[5], pk[7]);
    pbu.u[0] = pk[0]; pbu.u[1] = pk[1]; pbu.u[2] = pk[2]; pbu.u[3] = pk[3]; pb[2] = pbu.v;
    pbu.u[0] = pk[4]; pbu.u[1] = pk[5]; pbu.u[2] = pk[6]; pbu.u[3] = pk[7]; pb[3] = pbu.v;

    // ---- PV as O^T += V^T P^T: A = VB rows (d = dt*32+lc), straight from global/L2 ----
#pragma unroll
    for (int dt = 0; dt < 4; ++dt) {
      const ushort* vrow = VB + (size_t)(dt * 32 + lc) * SKV + kv0 + hi * 8;
#pragma unroll
      for (int cc = 0; cc < 4; ++cc) {
        bf16x8 va = *(const bf16x8*)(vrow + cc * 16);
        Ot[dt] = __builtin_amdgcn_mfma_f32_32x32x16_bf16(va, pb[cc], Ot[dt], 0, 0, 0);
      }
    }

    if (more) WRITELDS(cur ^ 1);  // nobody reads buf cur^1 until after this barrier
    __syncthreads();
    cur ^= 1;
  }

  // ---- epilogue: O^T regs -> row-major O partial; d = (r&3) + 8*(r>>2) + 4*hi ----
  float* Op = Opart + (size_t)split * SQ * D + (size_t)qrow * D;
#pragma unroll
  for (int dt = 0; dt < 4; ++dt) {
#pragma unroll
    for (int rg = 0; rg < 4; ++rg) {
      f32x4 o4 = { Ot[dt][4 * rg + 0], Ot[dt][4 * rg + 1],
                   Ot[dt][4 * rg + 2], Ot[dt][4 * rg + 3] };
      *(f32x4*)(Op + dt * 32 + rg * 8 + hi * 4) = o4;
    }
  }
  if (hi == 0) {
    Mst[split * SQ + qrow] = mrun;
    Lst[split * SQ + qrow] = lrun;
  }
}

__global__ void combine(const float* __restrict__ Opart, const float* __restrict__ Mst,
                        const float* __restrict__ Lst, float* __restrict__ out, int nsplit) {
  int idx = blockIdx.x * 256 + threadIdx.x;
  int qi = idx >> 7;
  float M = -INFINITY;
  for (int s = 0; s < nsplit; ++s) M = fmaxf(M, Mst[s * SQ + qi]);
  float num = 0.f, den = 0.f;
  for (int s = 0; s < nsplit; ++s) {
    float wgt = __expf(Mst[s * SQ + qi] - M);
    den += wgt * Lst[s * SQ + qi];
    num += wgt * Opart[(size_t)s * SQ * D + idx];
  }
  out[idx] = num / den;
}

extern "C" void kernel_launch(void* const* d_in, const int* in_sizes, int n_in,
                              void* d_out, int out_size, void* d_ws, size_t ws_size,
                              hipStream_t stream) {
  const float* q = (const float*)d_in[0];
  const float* k = (const float*)d_in[1];
  const float* v = (const float*)d_in[2];
  float* out = (float*)d_out;

  char* ws = (char*)d_ws;
  const size_t mat = (size_t)SQ * D * 2;  // 2 MB per bf16 matrix
  ushort* QThi = (ushort*)(ws);
  ushort* QTlo = (ushort*)(ws + mat);
  ushort* KThi = (ushort*)(ws + 2 * mat);
  ushort* KTlo = (ushort*)(ws + 3 * mat);
  ushort* VB   = (ushort*)(ws + 4 * mat);
  char* rest = ws + 5 * mat;
  size_t avail = (ws_size > 5 * mat) ? (ws_size - 5 * mat) : 0;

  const size_t opartSz = (size_t)SQ * D * 4;  // 4 MB per split
  const size_t statSz  = (size_t)SQ * 4;
  int nsplit = 8;   // grid 64 x 8 = 512 blocks = 2 blocks/CU (64KB LDS each)
  while (nsplit > 1 && (size_t)nsplit * (opartSz + 2 * statSz) > avail) nsplit >>= 1;

  float* Opart = (float*)rest;
  float* Mst = (float*)(rest + (size_t)nsplit * opartSz);
  float* Lst = (float*)(rest + (size_t)nsplit * opartSz + (size_t)nsplit * statSz);

  prep_transpose<<<dim3(SQ / 32, D / 32), 256, 0, stream>>>(q, QThi, QTlo);
  prep_transpose<<<dim3(SKV / 32, D / 32), 256, 0, stream>>>(k, KThi, KTlo);
  conv_v<<<(D * SKV) / (256 * 4), 256, 0, stream>>>(v, VB);
  flash_fwd<<<dim3(SQ / BQ, nsplit), 256, 0, stream>>>(QThi, QTlo, KThi, KTlo, VB,
                                                       Opart, Mst, Lst, SKV / nsplit);
  combine<<<(SQ * D) / 256, 256, 0, stream>>>(Opart, Mst, Lst, out, nsplit);
}

// Round 5
// 111.509 us; speedup vs baseline: 2.0443x; 1.0988x over previous
//
#include <hip/hip_runtime.h>
#include <hip/hip_bf16.h>
#include <math.h>

typedef short bf16x8 __attribute__((ext_vector_type(8)));
typedef float f32x4 __attribute__((ext_vector_type(4)));
typedef float f32x16 __attribute__((ext_vector_type(16)));

#define D 128
#define SQ 8192
#define SKV 8192
#define BQ 128    // q-rows per block (4 waves x 32)
#define BKV 64
#define LOG2E 1.4426950408889634f
#define DEFER_THR 11.5417f   // 8 * log2(e): e^8 bound in exp2 domain

__device__ __forceinline__ ushort f2bf(float x) {
  union { float f; unsigned u; } v; v.f = x;
  unsigned r = v.u + 0x7fffu + ((v.u >> 16) & 1u);
  return (ushort)(r >> 16);
}
__device__ __forceinline__ float bf2f(ushort h) {
  union { unsigned u; float f; } v; v.u = ((unsigned)h) << 16;
  return v.f;
}
// HW pack: dst = {hi: bf16(b), lo: bf16(a)} (RNE) — no builtin on gfx950, inline asm
__device__ __forceinline__ unsigned cvtpk(float a, float b) {
  unsigned r;
  asm("v_cvt_pk_bf16_f32 %0, %1, %2" : "=v"(r) : "v"(a), "v"(b));
  return r;
}
// native exp2
__device__ __forceinline__ float fexp2(float x) {
  float r;
  asm("v_exp_f32 %0, %1" : "=v"(r) : "v"(x));
  return r;
}
// v_permlane32_swap_b32: swaps a.lanes[32:63] <-> b.lanes[0:31]
__device__ __forceinline__ void pl32swap(unsigned& a, unsigned& b) {
  asm("v_permlane32_swap_b32 %0, %1" : "+v"(a), "+v"(b));
}

// (D x S) f32 row-major -> (S x D) bf16 hi/lo row-major (transpose + scale + split)
__global__ void prep_transpose(const float* __restrict__ src,
                               ushort* __restrict__ dhi, ushort* __restrict__ dlo,
                               float scale) {
  __shared__ float tile[32][33];
  int s0 = blockIdx.x * 32;
  int d0 = blockIdx.y * 32;
  int t = threadIdx.x;
  int g = t >> 5, l = t & 31;
#pragma unroll
  for (int j = 0; j < 4; ++j) {
    int dl = g * 4 + j;
    tile[dl][l] = src[(size_t)(d0 + dl) * SQ + s0 + l];
  }
  __syncthreads();
#pragma unroll
  for (int j = 0; j < 4; ++j) {
    int sl = g * 4 + j;
    float x = tile[l][sl] * scale;
    ushort hi = f2bf(x);
    float lo = x - bf2f(hi);
    dhi[(size_t)(s0 + sl) * D + d0 + l] = hi;
    dlo[(size_t)(s0 + sl) * D + d0 + l] = f2bf(lo);
  }
}

// plain f32 -> bf16 convert (keeps (D x SKV) layout == V^T A-frag layout)
__global__ void conv_v(const float* __restrict__ src, ushort* __restrict__ dst) {
  int i = (blockIdx.x * 256 + threadIdx.x) * 4;
  float4 v = *(const float4*)(src + i);
  ushort4 o;
  o.x = f2bf(v.x); o.y = f2bf(v.y); o.z = f2bf(v.z); o.w = f2bf(v.w);
  *(ushort4*)(dst + i) = o;
}

__global__ __launch_bounds__(256, 2)
void flash_fwd(const ushort* __restrict__ QThi, const ushort* __restrict__ QTlo,
               const ushort* __restrict__ KThi, const ushort* __restrict__ KTlo,
               const ushort* __restrict__ VB,
               float* __restrict__ Opart, float* __restrict__ Mst,
               float* __restrict__ Lst, int splitLen) {
  // K tiles 64x128 bf16 hi/lo, double-buffered. Staged via global_load_lds
  // (linear LDS dest) with PRE-SWIZZLED global source; reads use chunk ^= (row&15)
  // so A-frag b128 reads have <=4 lanes per 16B slot (2 per 16-lane phase).
  __shared__ ushort Khi[2][64][128];
  __shared__ ushort Klo[2][64][128];

  const int tid = threadIdx.x;
  const int w = tid >> 6;
  const int lane = tid & 63;
  const int lc = lane & 31;   // q-row owner (QK C-col) / kv-row (QK A) / d-row (PV A)
  const int hi = lane >> 5;
  const int qb = blockIdx.x;
  const int split = blockIdx.y;
  const int qrow = qb * BQ + w * 32 + lc;

  // Q B-frags (col = q = lc, k = d = ds*16 + hi*8 + j), contiguous in QT(SQ x D).
  // Q pre-scaled by log2e -> logits in exp2 domain.
  bf16x8 qh[8], ql[8];
#pragma unroll
  for (int ds = 0; ds < 8; ++ds) {
    qh[ds] = *(const bf16x8*)(QThi + (size_t)qrow * D + ds * 16 + hi * 8);
    ql[ds] = *(const bf16x8*)(QTlo + (size_t)qrow * D + ds * 16 + hi * 8);
  }

  // O^T accumulators: 4 d-tiles of 32; C col = q = lc, row = d
  f32x16 Ot[4];
#pragma unroll
  for (int dt = 0; dt < 4; ++dt)
#pragma unroll
    for (int e = 0; e < 16; ++e) Ot[dt][e] = 0.f;
  float mrun = -INFINITY, lrun = 0.f;

  const int kvBase = split * splitLen;
  const int nsteps = splitLen / BKV;

  // ---- async staging: 32 KB (hi+lo) = 32 x 1KB wave-chunks, 8 per wave ----
#define STAGE(NB, KV0)                                                        \
  {                                                                           \
    _Pragma("unroll")                                                         \
    for (int j = 0; j < 8; ++j) {                                             \
      int cblk = w * 8 + j;             /* 0..31; <16 -> hi, >=16 -> lo */    \
      int cc = cblk & 15;                                                     \
      const ushort* gbase = (cblk >> 4) ? KTlo : KThi;                        \
      char* lbase = (char*)((cblk >> 4) ? &Klo[NB][0][0] : &Khi[NB][0][0]);   \
      int r = cc * 4 + (lane >> 4);                                           \
      int s = lane & 15;                                                      \
      const ushort* gp = gbase + (size_t)((KV0) + r) * D + (s ^ (r & 15)) * 8;\
      __builtin_amdgcn_global_load_lds(                                       \
          (const __attribute__((address_space(1))) unsigned*)gp,              \
          (__attribute__((address_space(3))) unsigned*)(lbase + cc * 1024),   \
          16, 0, 0);                                                          \
    }                                                                         \
  }

  STAGE(0, kvBase);
  __syncthreads();
  int cur = 0;

  const int rswz = (lc & 15) << 4;

  for (int it = 0; it < nsteps; ++it) {
    const int kv0 = kvBase + it * BKV;
    const bool more = (it + 1 < nsteps);
    if (more) STAGE(cur ^ 1, kv0 + BKV);  // in flight across the whole step

    // ---- S^T = K Q^T (swapped): A = K^T rows (kv = t*32+lc), B = Q. 3-term split ----
    f32x16 s0, s1;
#pragma unroll
    for (int e = 0; e < 16; ++e) { s0[e] = 0.f; s1[e] = 0.f; }
    const char* khB = (const char*)&Khi[cur][0][0];
    const char* klB = (const char*)&Klo[cur][0][0];
#pragma unroll
    for (int ds = 0; ds < 8; ++ds) {
      const int col = (ds * 32 + hi * 16) ^ rswz;   // (row&15)==lc&15 for both kv tiles
      bf16x8 kh0 = *(const bf16x8*)(khB + lc * 256 + col);
      bf16x8 kl0 = *(const bf16x8*)(klB + lc * 256 + col);
      bf16x8 kh1 = *(const bf16x8*)(khB + (32 + lc) * 256 + col);
      bf16x8 kl1 = *(const bf16x8*)(klB + (32 + lc) * 256 + col);
      s0 = __builtin_amdgcn_mfma_f32_32x32x16_bf16(kh0, qh[ds], s0, 0, 0, 0);
      s0 = __builtin_amdgcn_mfma_f32_32x32x16_bf16(kh0, ql[ds], s0, 0, 0, 0);
      s0 = __builtin_amdgcn_mfma_f32_32x32x16_bf16(kl0, qh[ds], s0, 0, 0, 0);
      s1 = __builtin_amdgcn_mfma_f32_32x32x16_bf16(kh1, qh[ds], s1, 0, 0, 0);
      s1 = __builtin_amdgcn_mfma_f32_32x32x16_bf16(kh1, ql[ds], s1, 0, 0, 0);
      s1 = __builtin_amdgcn_mfma_f32_32x32x16_bf16(kl1, qh[ds], s1, 0, 0, 0);
    }

    // ---- in-register online softmax (exp2 domain); tree reductions ----
    float t8[8];
#pragma unroll
    for (int e = 0; e < 8; ++e)
      t8[e] = fmaxf(fmaxf(s0[e], s0[e + 8]), fmaxf(s1[e], s1[e + 8]));
    float t4a = fmaxf(t8[0], t8[4]), t4b = fmaxf(t8[1], t8[5]);
    float t4c = fmaxf(t8[2], t8[6]), t4d = fmaxf(t8[3], t8[7]);
    float mx = fmaxf(fmaxf(t4a, t4b), fmaxf(t4c, t4d));
    mx = fmaxf(mx, __shfl_xor(mx, 32));

    // defer-max (T13): skip O/l rescale while tile max within e^8 of running max
    if (!__all(mx - mrun <= DEFER_THR)) {
      float mn = fmaxf(mrun, mx);
      float sc = fexp2(mrun - mn);   // first iter: exp2(-inf) = 0
      mrun = mn;
      lrun *= sc;
#pragma unroll
      for (int dt = 0; dt < 4; ++dt)
#pragma unroll
        for (int e = 0; e < 16; ++e) Ot[dt][e] *= sc;
    }

#pragma unroll
    for (int e = 0; e < 16; ++e) {
      s0[e] = fexp2(s0[e] - mrun);
      s1[e] = fexp2(s1[e] - mrun);
    }
    float a8[8];
#pragma unroll
    for (int e = 0; e < 8; ++e) a8[e] = (s0[e] + s0[e + 8]) + (s1[e] + s1[e + 8]);
    float lsum = ((a8[0] + a8[4]) + (a8[1] + a8[5])) + ((a8[2] + a8[6]) + (a8[3] + a8[7]));
    lsum += __shfl_xor(lsum, 32);
    lrun += lsum;

    // ---- P -> bf16 B-frags in-register (T12: cvt_pk + permlane32_swap) ----
    unsigned pk[8];
    bf16x8 pb[4];
    union { unsigned u[4]; bf16x8 v; } pbu;
#pragma unroll
    for (int j = 0; j < 8; ++j) pk[j] = cvtpk(s0[2 * j], s0[2 * j + 1]);
    pl32swap(pk[0], pk[2]); pl32swap(pk[1], pk[3]);
    pl32swap(pk[4], pk[6]); pl32swap(pk[5], pk[7]);
    pbu.u[0] = pk[0]; pbu.u[1] = pk[1]; pbu.u[2] = pk[2]; pbu.u[3] = pk[3]; pb[0] = pbu.v;
    pbu.u[0] = pk[4]; pbu.u[1] = pk[5]; pbu.u[2] = pk[6]; pbu.u[3] = pk[7]; pb[1] = pbu.v;
#pragma unroll
    for (int j = 0; j < 8; ++j) pk[j] = cvtpk(s1[2 * j], s1[2 * j + 1]);
    pl32swap(pk[0], pk[2]); pl32swap(pk[1], pk[3]);
    pl32swap(pk[4], pk[6]); pl32swap(pk[5], pk[7]);
    pbu.u[0] = pk[0]; pbu.u[1] = pk[1]; pbu.u[2] = pk[2]; pbu.u[3] = pk[3]; pb[2] = pbu.v;
    pbu.u[0] = pk[4]; pbu.u[1] = pk[5]; pbu.u[2] = pk[6]; pbu.u[3] = pk[7]; pb[3] = pbu.v;

    // ---- PV as O^T += V^T P^T: A = VB rows (d = dt*32+lc), direct from L2 ----
#pragma unroll
    for (int dt = 0; dt < 4; ++dt) {
      const ushort* vrow = VB + (size_t)(dt * 32 + lc) * SKV + kv0 + hi * 8;
#pragma unroll
      for (int cc = 0; cc < 4; ++cc) {
        bf16x8 va = *(const bf16x8*)(vrow + cc * 16);
        Ot[dt] = __builtin_amdgcn_mfma_f32_32x32x16_bf16(va, pb[cc], Ot[dt], 0, 0, 0);
      }
    }

    __syncthreads();   // compiler drains vmcnt before barrier -> staged tile ready
    cur ^= 1;
  }

  // ---- epilogue: O^T regs -> row-major O partial; d = dt*32 + rg*8 + hi*4 + e ----
  float* Op = Opart + (size_t)split * SQ * D + (size_t)qrow * D;
#pragma unroll
  for (int dt = 0; dt < 4; ++dt) {
#pragma unroll
    for (int rg = 0; rg < 4; ++rg) {
      f32x4 o4 = { Ot[dt][4 * rg + 0], Ot[dt][4 * rg + 1],
                   Ot[dt][4 * rg + 2], Ot[dt][4 * rg + 3] };
      *(f32x4*)(Op + dt * 32 + rg * 8 + hi * 4) = o4;
    }
  }
  if (hi == 0) {
    Mst[split * SQ + qrow] = mrun;   // log2-domain
    Lst[split * SQ + qrow] = lrun;
  }
}

__global__ void combine(const float* __restrict__ Opart, const float* __restrict__ Mst,
                        const float* __restrict__ Lst, float* __restrict__ out, int nsplit) {
  int idx = blockIdx.x * 256 + threadIdx.x;
  int qi = idx >> 7;
  float M = -INFINITY;
  for (int s = 0; s < nsplit; ++s) M = fmaxf(M, Mst[s * SQ + qi]);
  float num = 0.f, den = 0.f;
  for (int s = 0; s < nsplit; ++s) {
    float wgt = fexp2(Mst[s * SQ + qi] - M);   // stats are log2-domain
    den += wgt * Lst[s * SQ + qi];
    num += wgt * Opart[(size_t)s * SQ * D + idx];
  }
  out[idx] = num / den;
}

extern "C" void kernel_launch(void* const* d_in, const int* in_sizes, int n_in,
                              void* d_out, int out_size, void* d_ws, size_t ws_size,
                              hipStream_t stream) {
  const float* q = (const float*)d_in[0];
  const float* k = (const float*)d_in[1];
  const float* v = (const float*)d_in[2];
  float* out = (float*)d_out;

  char* ws = (char*)d_ws;
  const size_t mat = (size_t)SQ * D * 2;  // 2 MB per bf16 matrix
  ushort* QThi = (ushort*)(ws);
  ushort* QTlo = (ushort*)(ws + mat);
  ushort* KThi = (ushort*)(ws + 2 * mat);
  ushort* KTlo = (ushort*)(ws + 3 * mat);
  ushort* VB   = (ushort*)(ws + 4 * mat);
  char* rest = ws + 5 * mat;
  size_t avail = (ws_size > 5 * mat) ? (ws_size - 5 * mat) : 0;

  const size_t opartSz = (size_t)SQ * D * 4;  // 4 MB per split
  const size_t statSz  = (size_t)SQ * 4;
  int nsplit = 8;   // grid 64 x 8 = 512 blocks = 2 blocks/CU (64KB LDS each)
  while (nsplit > 1 && (size_t)nsplit * (opartSz + 2 * statSz) > avail) nsplit >>= 1;

  float* Opart = (float*)rest;
  float* Mst = (float*)(rest + (size_t)nsplit * opartSz);
  float* Lst = (float*)(rest + (size_t)nsplit * opartSz + (size_t)nsplit * statSz);

  prep_transpose<<<dim3(SQ / 32, D / 32), 256, 0, stream>>>(q, QThi, QTlo, LOG2E);
  prep_transpose<<<dim3(SKV / 32, D / 32), 256, 0, stream>>>(k, KThi, KTlo, 1.0f);
  conv_v<<<(D * SKV) / (256 * 4), 256, 0, stream>>>(v, VB);
  flash_fwd<<<dim3(SQ / BQ, nsplit), 256, 0, stream>>>(QThi, QTlo, KThi, KTlo, VB,
                                                       Opart, Mst, Lst, SKV / nsplit);
  combine<<<(SQ * D) / 256, 256, 0, stream>>>(Opart, Mst, Lst, out, nsplit);
}

// Round 8
// 77.463 us; speedup vs baseline: 2.9427x; 1.4395x over previous
//
#include <hip/hip_runtime.h>
#include <hip/hip_bf16.h>
#include <math.h>

typedef _Float16 half8 __attribute__((ext_vector_type(8)));
typedef _Float16 half4v __attribute__((ext_vector_type(4)));
typedef __fp16 fp16x2 __attribute__((ext_vector_type(2)));
typedef float f32x4 __attribute__((ext_vector_type(4)));
typedef float f32x16 __attribute__((ext_vector_type(16)));

#define D 128
#define SQ 8192
#define SKV 8192
#define BQ 128    // q-rows per block (4 waves x 32)
#define BKV 64
#define LOG2E 1.4426950408889634f
#define DEFER_THR 11.5417f   // 8 * log2(e); P <= 2^11.54 ~ 2981 < f16 max

__device__ __forceinline__ ushort f2bf(float x) {
  union { float f; unsigned u; } v; v.f = x;
  unsigned r = v.u + 0x7fffu + ((v.u >> 16) & 1u);
  return (ushort)(r >> 16);
}
__device__ __forceinline__ float bf2f(ushort h) {
  union { unsigned u; float f; } v; v.u = ((unsigned)h) << 16;
  return v.f;
}
// bf16 pack (for O partials)
__device__ __forceinline__ unsigned cvtpk_bf(float a, float b) {
  unsigned r;
  asm("v_cvt_pk_bf16_f32 %0, %1, %2" : "=v"(r) : "v"(a), "v"(b));
  return r;
}
// f16 pack (HW single-instr, RTZ)
__device__ __forceinline__ unsigned cvtpk_h(float a, float b) {
  union { fp16x2 h; unsigned u; } r;
  r.h = __builtin_amdgcn_cvt_pkrtz(a, b);
  return r.u;
}
__device__ __forceinline__ float fexp2(float x) {
  float r;
  asm("v_exp_f32 %0, %1" : "=v"(r) : "v"(x));
  return r;
}
__device__ __forceinline__ void pl32swap(unsigned& a, unsigned& b) {
  asm("v_permlane32_swap_b32 %0, %1" : "+v"(a), "+v"(b));
}

// q: (D x SQ) f32 -> QT (SQ x D) f16 row-major, scaled by log2e
__global__ void prep_q(const float* __restrict__ src, _Float16* __restrict__ dst) {
  __shared__ float tile[32][33];
  int s0 = blockIdx.x * 32, d0 = blockIdx.y * 32;
  int t = threadIdx.x, g = t >> 5, l = t & 31;
#pragma unroll
  for (int j = 0; j < 4; ++j)
    tile[g * 4 + j][l] = src[(size_t)(d0 + g * 4 + j) * SQ + s0 + l];
  __syncthreads();
#pragma unroll
  for (int j = 0; j < 4; ++j) {
    int sl = g * 4 + j;
    dst[(size_t)(s0 + sl) * D + d0 + l] = (_Float16)(tile[l][sl] * LOG2E);
  }
}

// k: (D x SKV) f32 -> PK packed A-frag order (f16):
// elem = (kvt*8 + dcol/16)*512 + (((dcol>>3)&1)*32 + (srow&31))*8 + (dcol&7)
__global__ void prep_k(const float* __restrict__ src, _Float16* __restrict__ dst) {
  __shared__ float tile[32][33];
  int s0 = blockIdx.x * 32, d0 = blockIdx.y * 32;
  int t = threadIdx.x, g = t >> 5, l = t & 31;
#pragma unroll
  for (int j = 0; j < 4; ++j)
    tile[g * 4 + j][l] = src[(size_t)(d0 + g * 4 + j) * SKV + s0 + l];
  __syncthreads();
#pragma unroll
  for (int j = 0; j < 4; ++j) {
    int srow = s0 + g * 4 + j;
    int dcol = d0 + l;
    size_t elem = (size_t)((srow >> 5) * 8 + (dcol >> 4)) * 512 +
                  (((dcol >> 3) & 1) * 32 + (srow & 31)) * 8 + (dcol & 7);
    dst[elem] = (_Float16)tile[l][g * 4 + j];
  }
}

// v: (D x SKV) f32 -> PV packed A-frag order (f16):
// elem = kvb*8192 + ((drow>>5)*4 + ((kv>>4)&3))*512 + (((kv>>3)&1)*32 + (drow&31))*8 + (kv&7)
__global__ void prep_v(const float* __restrict__ src, _Float16* __restrict__ dst) {
  int i4 = (blockIdx.x * 256 + threadIdx.x) * 4;
  float4 v = *(const float4*)(src + i4);
  int drow = i4 >> 13;          // / SKV
  int kv = i4 & (SKV - 1);
  size_t elem = (size_t)(kv >> 6) * 8192 +
                (size_t)((drow >> 5) * 4 + ((kv >> 4) & 3)) * 512 +
                (((kv >> 3) & 1) * 32 + (drow & 31)) * 8 + (kv & 7);
  half4v o = { (_Float16)v.x, (_Float16)v.y, (_Float16)v.z, (_Float16)v.w };
  *(half4v*)(dst + elem) = o;
}

// Barrier-free flash: no LDS, waves fully independent; K/V read from L1/L2
// as pre-packed contiguous 1KB wave-fragments. All matmuls f16.
__global__ __launch_bounds__(256, 2)
void flash_fwd(const _Float16* __restrict__ QT, const _Float16* __restrict__ PK,
               const _Float16* __restrict__ PV,
               ushort* __restrict__ Opart, float* __restrict__ Mst,
               float* __restrict__ Lst, int splitLen) {
  const int tid = threadIdx.x;
  const int w = tid >> 6;
  const int lane = tid & 63;
  const int lc = lane & 31;
  const int hi = lane >> 5;
  const int qb = blockIdx.x;
  const int split = blockIdx.y;
  const int qrow = qb * BQ + w * 32 + lc;

  // Q B-frags (col = q = lc, k-dim = d), pre-scaled by log2e
  half8 qh[8];
#pragma unroll
  for (int ds = 0; ds < 8; ++ds)
    qh[ds] = *(const half8*)(QT + (size_t)qrow * D + ds * 16 + hi * 8);

  f32x16 Ot[4];
#pragma unroll
  for (int dt = 0; dt < 4; ++dt)
#pragma unroll
    for (int e = 0; e < 16; ++e) Ot[dt][e] = 0.f;
  float mrun = -INFINITY, lrun = 0.f;

  const int kvBase = split * splitLen;
  const int nsteps = splitLen / BKV;

  // packed pointers: advance 64*128 elements per step
  const _Float16* kp = PK + (size_t)kvBase * D + lane * 8;
  const _Float16* vp = PV + (size_t)kvBase * D + lane * 8;

  for (int it = 0; it < nsteps; ++it) {
    // ---- K A-frags: 16 contiguous 1KB wave-loads ----
    half8 ka0[8], ka1[8];
#pragma unroll
    for (int ds = 0; ds < 8; ++ds) ka0[ds] = *(const half8*)(kp + ds * 512);
#pragma unroll
    for (int ds = 0; ds < 8; ++ds) ka1[ds] = *(const half8*)(kp + (8 + ds) * 512);

    // ---- S^T = K Q^T: single f16 term, 2 accumulator chains ----
    f32x16 s0, s1;
#pragma unroll
    for (int e = 0; e < 16; ++e) { s0[e] = 0.f; s1[e] = 0.f; }
    __builtin_amdgcn_s_setprio(1);
#pragma unroll
    for (int ds = 0; ds < 8; ++ds) {
      s0 = __builtin_amdgcn_mfma_f32_32x32x16_f16(ka0[ds], qh[ds], s0, 0, 0, 0);
      s1 = __builtin_amdgcn_mfma_f32_32x32x16_f16(ka1[ds], qh[ds], s1, 0, 0, 0);
    }
    __builtin_amdgcn_s_setprio(0);

    // ---- V A-frags issued now: L2 latency hides under softmax (~300 cyc) ----
    half8 va[16];
#pragma unroll
    for (int f = 0; f < 16; ++f) va[f] = *(const half8*)(vp + f * 512);

    // ---- in-register online softmax (exp2 domain), tree reductions ----
    float t8[8];
#pragma unroll
    for (int e = 0; e < 8; ++e)
      t8[e] = fmaxf(fmaxf(s0[e], s0[e + 8]), fmaxf(s1[e], s1[e + 8]));
    float mx = fmaxf(fmaxf(fmaxf(t8[0], t8[4]), fmaxf(t8[1], t8[5])),
                     fmaxf(fmaxf(t8[2], t8[6]), fmaxf(t8[3], t8[7])));
    mx = fmaxf(mx, __shfl_xor(mx, 32));

    if (!__all(mx - mrun <= DEFER_THR)) {     // defer-max (T13)
      float mn = fmaxf(mrun, mx);
      float sc = fexp2(mrun - mn);            // first iter: exp2(-inf)=0
      mrun = mn;
      lrun *= sc;
#pragma unroll
      for (int dt = 0; dt < 4; ++dt)
#pragma unroll
        for (int e = 0; e < 16; ++e) Ot[dt][e] *= sc;
    }

#pragma unroll
    for (int e = 0; e < 16; ++e) {
      s0[e] = fexp2(s0[e] - mrun);
      s1[e] = fexp2(s1[e] - mrun);
    }
    float a8[8];
#pragma unroll
    for (int e = 0; e < 8; ++e) a8[e] = (s0[e] + s0[e + 8]) + (s1[e] + s1[e + 8]);
    float lsum = ((a8[0] + a8[4]) + (a8[1] + a8[5])) +
                 ((a8[2] + a8[6]) + (a8[3] + a8[7]));
    lsum += __shfl_xor(lsum, 32);
    lrun += lsum;

    // ---- P -> f16 B-frags in-register (T12: cvt_pkrtz + permlane32_swap) ----
    unsigned pk[8];
    half8 pb[4];
    union { unsigned u[4]; half8 v; } pbu;
#pragma unroll
    for (int j = 0; j < 8; ++j) pk[j] = cvtpk_h(s0[2 * j], s0[2 * j + 1]);
    pl32swap(pk[0], pk[2]); pl32swap(pk[1], pk[3]);
    pl32swap(pk[4], pk[6]); pl32swap(pk[5], pk[7]);
    pbu.u[0] = pk[0]; pbu.u[1] = pk[1]; pbu.u[2] = pk[2]; pbu.u[3] = pk[3]; pb[0] = pbu.v;
    pbu.u[0] = pk[4]; pbu.u[1] = pk[5]; pbu.u[2] = pk[6]; pbu.u[3] = pk[7]; pb[1] = pbu.v;
#pragma unroll
    for (int j = 0; j < 8; ++j) pk[j] = cvtpk_h(s1[2 * j], s1[2 * j + 1]);
    pl32swap(pk[0], pk[2]); pl32swap(pk[1], pk[3]);
    pl32swap(pk[4], pk[6]); pl32swap(pk[5], pk[7]);
    pbu.u[0] = pk[0]; pbu.u[1] = pk[1]; pbu.u[2] = pk[2]; pbu.u[3] = pk[3]; pb[2] = pbu.v;
    pbu.u[0] = pk[4]; pbu.u[1] = pk[5]; pbu.u[2] = pk[6]; pbu.u[3] = pk[7]; pb[3] = pbu.v;

    // ---- PV: O^T += V^T P^T ----
    __builtin_amdgcn_s_setprio(1);
#pragma unroll
    for (int cc = 0; cc < 4; ++cc) {
      Ot[0] = __builtin_amdgcn_mfma_f32_32x32x16_f16(va[0 * 4 + cc], pb[cc], Ot[0], 0, 0, 0);
      Ot[1] = __builtin_amdgcn_mfma_f32_32x32x16_f16(va[1 * 4 + cc], pb[cc], Ot[1], 0, 0, 0);
      Ot[2] = __builtin_amdgcn_mfma_f32_32x32x16_f16(va[2 * 4 + cc], pb[cc], Ot[2], 0, 0, 0);
      Ot[3] = __builtin_amdgcn_mfma_f32_32x32x16_f16(va[3 * 4 + cc], pb[cc], Ot[3], 0, 0, 0);
    }
    __builtin_amdgcn_s_setprio(0);

    kp += (size_t)BKV * D;
    vp += (size_t)BKV * D;
  }

  // ---- epilogue: bf16 partials; d = dt*32 + rg*8 + hi*4 + e ----
  ushort* Op = Opart + (size_t)split * SQ * D + (size_t)qrow * D;
#pragma unroll
  for (int dt = 0; dt < 4; ++dt) {
#pragma unroll
    for (int rg = 0; rg < 4; ++rg) {
      uint2 o2;
      o2.x = cvtpk_bf(Ot[dt][4 * rg + 0], Ot[dt][4 * rg + 1]);
      o2.y = cvtpk_bf(Ot[dt][4 * rg + 2], Ot[dt][4 * rg + 3]);
      *(uint2*)(Op + dt * 32 + rg * 8 + hi * 4) = o2;
    }
  }
  if (hi == 0) {
    Mst[split * SQ + qrow] = mrun;   // log2-domain
    Lst[split * SQ + qrow] = lrun;
  }
}

__global__ void combine(const ushort* __restrict__ Opart, const float* __restrict__ Mst,
                        const float* __restrict__ Lst, float* __restrict__ out, int nsplit) {
  int t4 = (blockIdx.x * 256 + threadIdx.x) * 4;
  int qi = t4 >> 7;
  float M = -INFINITY;
  for (int s = 0; s < nsplit; ++s) M = fmaxf(M, Mst[s * SQ + qi]);
  float n0 = 0.f, n1 = 0.f, n2 = 0.f, n3 = 0.f, den = 0.f;
  for (int s = 0; s < nsplit; ++s) {
    float wgt = fexp2(Mst[s * SQ + qi] - M);
    den += wgt * Lst[s * SQ + qi];
    ushort4 u = *(const ushort4*)(Opart + (size_t)s * SQ * D + t4);
    n0 += wgt * bf2f(u.x); n1 += wgt * bf2f(u.y);
    n2 += wgt * bf2f(u.z); n3 += wgt * bf2f(u.w);
  }
  float inv = 1.0f / den;
  float4 o = { n0 * inv, n1 * inv, n2 * inv, n3 * inv };
  *(float4*)(out + t4) = o;
}

extern "C" void kernel_launch(void* const* d_in, const int* in_sizes, int n_in,
                              void* d_out, int out_size, void* d_ws, size_t ws_size,
                              hipStream_t stream) {
  const float* q = (const float*)d_in[0];
  const float* k = (const float*)d_in[1];
  const float* v = (const float*)d_in[2];
  float* out = (float*)d_out;

  char* ws = (char*)d_ws;
  const size_t mat = (size_t)SQ * D * 2;   // 2 MB per f16 matrix
  _Float16* QT = (_Float16*)(ws);
  _Float16* PK = (_Float16*)(ws + mat);
  _Float16* PV = (_Float16*)(ws + 2 * mat);
  char* rest = ws + 3 * mat;

  const size_t opartSz = (size_t)SQ * D * 2;  // bf16 partials: 2 MB per split
  const size_t statSz  = (size_t)SQ * 4;
  int nsplit = 16;   // grid 64 x 16 = 1024 blocks
  while (nsplit > 1 &&
         3 * mat + (size_t)nsplit * (opartSz + 2 * statSz) > ws_size) nsplit >>= 1;

  ushort* Opart = (ushort*)rest;
  float* Mst = (float*)(rest + (size_t)nsplit * opartSz);
  float* Lst = (float*)(rest + (size_t)nsplit * opartSz + (size_t)nsplit * statSz);

  prep_q<<<dim3(SQ / 32, D / 32), 256, 0, stream>>>(q, QT);
  prep_k<<<dim3(SKV / 32, D / 32), 256, 0, stream>>>(k, PK);
  prep_v<<<(D * SKV) / (256 * 4), 256, 0, stream>>>(v, PV);
  flash_fwd<<<dim3(SQ / BQ, nsplit), 256, 0, stream>>>(QT, PK, PV,
                                                       Opart, Mst, Lst, SKV / nsplit);
  combine<<<(SQ * D) / (256 * 4), 256, 0, stream>>>(Opart, Mst, Lst, out, nsplit);
}